// Round 5
// baseline (359.986 us; speedup 1.0000x reference)
//
// AttentionModel: fused QKV projection + causal softmax attention, MI355X/gfx950.
// Round 8: amortize the per-phase fixed cost (R4-R7: ~7K cy/phase vs ~500 cy of
// work, invariant to sync scheme) by DOUBLING work per phase in scores/pv.
//  - run_kloop_dA: A-operand read DIRECTLY from global (half8/lane fragments,
//    64B row segments, L2/L3-hot) -> no A staging. Freed LDS -> 256-row B tile.
//    Block output 128x256, acc[4][8], 64 MFMA/phase (was 16). Phase-slots halve.
//  - k_scores: kt-PAIRS (sub-tile == wn), 576 blocks heavy-first; causal mask
//    on diagonal sub-tile; overshoot sub-tile (kt>qt) not stored.
//  - k_pv: dt-pairs (output 128x256 of Out), 256 blocks, qt interleaved.
//  - R7 fusion REVERTED (P exp'd 4x redundantly in-loop on transcendental unit
//    = regression); k_softmax restored (streams P once, near HBM roofline).
//  - k_proj kept from R7 (V written direct-transposed; k_trans deleted).
// ws layout (bytes): P 0..64M | Qb 64M | Kb 80M | Vt 112M | Wf16 128M

#include <hip/hip_runtime.h>
#include <stdint.h>
#include <stddef.h>
#include <math.h>

typedef _Float16 half8 __attribute__((ext_vector_type(8)));
typedef float f32x4 __attribute__((ext_vector_type(4)));

#define SCALE_QK 0.04419417382415922f  // 1/sqrt(512)

__device__ __forceinline__ void gload16(const void* g, void* lds) {
  __builtin_amdgcn_global_load_lds(
      (const __attribute__((address_space(1))) void*)g,
      (__attribute__((address_space(3))) void*)lds,
      16, 0, 0);
}

// ---- proj K-loop: C[128x128] = A[128xK](fp32) * B^T, staged A (cvt f16), BK=64.
// LDS contract: element (row r, 8-group g) at halfword r*64 + (g^(r&7))*8.
__device__ __forceinline__ void run_kloop_proj(const float* Arow0, const _Float16* Brow0,
                                               int lda, int ldb, int kIters,
                                               _Float16* As0, _Float16* As1,
                                               _Float16* Bs0, _Float16* Bs1,
                                               f32x4 (&acc)[4][4])
{
  const int tid  = threadIdx.x;
  const int lane = tid & 63;
  const int w    = tid >> 6;
  const int wm   = w >> 1, wn = w & 1;
  const int srow = tid >> 3;
  const int sg   = tid & 7;
  const int swz  = sg ^ (srow & 7);
  const int fr   = lane & 15;
  const int fq   = lane >> 4;
  const int fx   = lane & 7;

  f32x4 preF[8];

  auto loadAreg = [&](int it) {
    const int k0 = it * 64;
    #pragma unroll
    for (int i = 0; i < 4; ++i) {
      const float* src = Arow0 + (size_t)(i*32 + srow) * lda + (k0 + sg*8);
      preF[2*i]   = *(const f32x4*)src;
      preF[2*i+1] = *(const f32x4*)(src + 4);
    }
  };
  auto writeA = [&](_Float16* dst) {
    #pragma unroll
    for (int i = 0; i < 4; ++i) {
      f32x4 x = preF[2*i], y = preF[2*i+1];
      half8 h;
      h[0]=(_Float16)x[0]; h[1]=(_Float16)x[1]; h[2]=(_Float16)x[2]; h[3]=(_Float16)x[3];
      h[4]=(_Float16)y[0]; h[5]=(_Float16)y[1]; h[6]=(_Float16)y[2]; h[7]=(_Float16)y[3];
      *(half8*)(dst + (i*32 + srow)*64 + swz*8) = h;
    }
  };
  auto gloadB = [&](int it, _Float16* dst) {
    const int k0 = it * 64;
    #pragma unroll
    for (int i = 0; i < 4; ++i)
      gload16(Brow0 + (size_t)(i*32 + srow) * ldb + (k0 + swz*8), dst + i*2048 + w*512);
  };
  auto compute = [&](const _Float16* cAs, const _Float16* cBs) {
    #pragma unroll
    for (int ks = 0; ks < 2; ++ks) {
      half8 av[4], bv[4];
      const int slot = (ks*4 + fq) ^ fx;
      #pragma unroll
      for (int i = 0; i < 4; ++i) {
        av[i] = *(const half8*)(cAs + (wm*64 + i*16 + fr)*64 + slot*8);
        bv[i] = *(const half8*)(cBs + (wn*64 + i*16 + fr)*64 + slot*8);
      }
      #pragma unroll
      for (int i = 0; i < 4; ++i) {
        #pragma unroll
        for (int j = 0; j < 4; ++j)
          acc[i][j] = __builtin_amdgcn_mfma_f32_16x16x32_f16(av[i], bv[j], acc[i][j], 0, 0, 0);
      }
    }
  };

  loadAreg(0);
  gloadB(0, Bs0);
  writeA(As0);
  __syncthreads();

  for (int it = 0; it < kIters; it += 2) {
    loadAreg(it + 1);
    gloadB(it + 1, Bs1);
    compute(As0, Bs0);
    writeA(As1);
    __syncthreads();
    const bool more = (it + 2) < kIters;
    if (more) { loadAreg(it + 2); gloadB(it + 2, Bs0); }
    compute(As1, Bs1);
    if (more) writeA(As0);
    __syncthreads();
  }
}

// ---- direct-A K-loop: C[128x256] = A[128xK](f16, global) * B^T, B staged [256][64].
// A fragments: half8 per lane straight from global (row = wm*64+i*16+fr,
// cols k0 + ks*32 + fq*8) -- no LDS for A. B staging/read identical swizzle
// contract to the proven zero-conflict 128-row version, rows extended to 256.
__device__ __forceinline__ void run_kloop_dA(const _Float16* Arow0, const _Float16* Brow0,
                                             int lda, int ldb, int kIters,
                                             _Float16* Bs0, _Float16* Bs1,
                                             f32x4 (&acc)[4][8])
{
  const int tid  = threadIdx.x;
  const int lane = tid & 63;
  const int w    = tid >> 6;
  const int wm   = w >> 1, wn = w & 1;
  const int srow = tid >> 3;
  const int sg   = tid & 7;
  const int swz  = sg ^ (srow & 7);
  const int fr   = lane & 15;
  const int fq   = lane >> 4;
  const int fx   = lane & 7;

  auto stageB = [&](int it, _Float16* dst) {
    const int k0 = it * 64;
    #pragma unroll
    for (int i = 0; i < 8; ++i)
      gload16(Brow0 + (size_t)(i*32 + srow) * ldb + (k0 + swz*8), dst + i*2048 + w*512);
  };
  auto compute = [&](const _Float16* cBs, int it) {
    const int k0 = it * 64;
    half8 av[2][4];
    #pragma unroll
    for (int ks = 0; ks < 2; ++ks)
      #pragma unroll
      for (int i = 0; i < 4; ++i)
        av[ks][i] = *(const half8*)(Arow0 + (size_t)(wm*64 + i*16 + fr)*lda + k0 + ks*32 + fq*8);
    #pragma unroll
    for (int ks = 0; ks < 2; ++ks) {
      half8 bv[8];
      const int slot = (ks*4 + fq) ^ fx;
      #pragma unroll
      for (int j = 0; j < 8; ++j)
        bv[j] = *(const half8*)(cBs + (wn*128 + j*16 + fr)*64 + slot*8);
      #pragma unroll
      for (int i = 0; i < 4; ++i)
        #pragma unroll
        for (int j = 0; j < 8; ++j)
          acc[i][j] = __builtin_amdgcn_mfma_f32_16x16x32_f16(av[ks][i], bv[j], acc[i][j], 0, 0, 0);
    }
  };

  stageB(0, Bs0);
  __syncthreads();
  for (int it = 0; it < kIters; it += 2) {
    stageB(it + 1, Bs1);
    compute(Bs0, it);
    __syncthreads();
    const bool more = (it + 2) < kIters;
    if (more) stageB(it + 2, Bs0);
    compute(Bs1, it + 1);
    __syncthreads();
  }
}

// ---- weights fp32 -> f16 (3 x 512x512 concatenated) ----
__global__ __launch_bounds__(256) void k_cvtw(const float* __restrict__ Wq,
                                              const float* __restrict__ Wk,
                                              const float* __restrict__ Wv,
                                              _Float16* __restrict__ Wb)
{
  const int t = blockIdx.x * 256 + threadIdx.x;
  const int base = t * 8;
  const int z = base >> 18;
  const int off = base & 262143;
  const float* src = (z == 0) ? Wq : ((z == 1) ? Wk : Wv);
  f32x4 a = *(const f32x4*)(src + off);
  f32x4 b = *(const f32x4*)(src + off + 4);
  half8 h;
  h[0]=(_Float16)a[0]; h[1]=(_Float16)a[1]; h[2]=(_Float16)a[2]; h[3]=(_Float16)a[3];
  h[4]=(_Float16)b[0]; h[5]=(_Float16)b[1]; h[6]=(_Float16)b[2]; h[7]=(_Float16)b[3];
  *(half8*)(Wb + base) = h;
}

// ---- projections: X[16384x512](fp32) @ W^T + bias -> f16; V direct-transposed ----
// 1D grid 1536: xcd = bid%8; panel p = xcd*48 + i/4; nt = i%4; z = p/128, mt = p%128.
__global__ __launch_bounds__(256) void k_proj(const float* __restrict__ q,
                                              const float* __restrict__ k,
                                              const float* __restrict__ v,
                                              const _Float16* __restrict__ Wb,
                                              const float* __restrict__ bq,
                                              const float* __restrict__ bk,
                                              const float* __restrict__ bv,
                                              _Float16* __restrict__ Qb,
                                              _Float16* __restrict__ Kb,
                                              _Float16* __restrict__ Vt)
{
  __shared__ __align__(16) _Float16 LDSbuf[4*128*64];   // 64 KB, carved
  _Float16* As0 = LDSbuf;
  _Float16* As1 = LDSbuf + 8192;
  _Float16* Bs0 = LDSbuf + 16384;
  _Float16* Bs1 = LDSbuf + 24576;

  const int bid = blockIdx.x;
  const int xcd = bid & 7, i = bid >> 3;
  const int p = xcd * 48 + (i >> 2);
  const int nt = i & 3;
  const int z = p >> 7, mt = p & 127;

  const float* A     = (z == 0) ? q  : (z == 1) ? k  : v;
  const float* bia   = (z == 0) ? bq : (z == 1) ? bk : bv;
  const _Float16* B  = Wb + (size_t)z * 512 * 512;

  f32x4 acc[4][4] = {};
  run_kloop_proj(A + (size_t)mt*128*512, B + (size_t)nt*128*512, 512, 512, 8,
                 As0, As1, Bs0, Bs1, acc);

  const int tid = threadIdx.x;
  const int lane = tid & 63, w = tid >> 6;
  const int wm = w >> 1, wn = w & 1;
  const int fr = lane & 15, fq = lane >> 4;   // C/D: col=lane&15, row=(lane>>4)*4+reg

  if (z < 2) {
    _Float16* C = (z == 0) ? Qb : Kb;
    #pragma unroll
    for (int j = 0; j < 4; ++j) {
      const int col = nt*128 + wn*64 + j*16 + fr;
      const float bval = bia[col];
      #pragma unroll
      for (int i2 = 0; i2 < 4; ++i2) {
        const int row = mt*128 + wm*64 + i2*16 + fq*4;
        #pragma unroll
        for (int r = 0; r < 4; ++r)
          C[(size_t)(row + r) * 512 + col] = (_Float16)(acc[i2][j][r] + bval);
      }
    }
  } else {
    // V: stage transposed tile in LDS [col 128][row 128+pad8], write Vt coalesced.
    _Float16* sm = LDSbuf;   // 128*136 halfs (kloop done; LDS free)
    #pragma unroll
    for (int j = 0; j < 4; ++j) {
      const int colloc = wn*64 + j*16 + fr;
      const float bval = bia[nt*128 + colloc];
      #pragma unroll
      for (int i2 = 0; i2 < 4; ++i2) {
        const int rowloc = wm*64 + i2*16 + fq*4;
        #pragma unroll
        for (int r = 0; r < 4; ++r)
          sm[colloc*136 + rowloc + r] = (_Float16)(acc[i2][j][r] + bval);
      }
    }
    __syncthreads();
    const int bb = mt >> 4, s0 = (mt & 15) * 128;
    #pragma unroll
    for (int q8 = 0; q8 < 8; ++q8) {
      const int dloc = q8*16 + (tid >> 4);
      const int ch   = tid & 15;
      half8 o = *(const half8*)&sm[dloc*136 + ch*8];
      *(half8*)(Vt + ((size_t)bb*512 + nt*128 + dloc)*2048 + s0 + ch*8) = o;
    }
  }
}

// ---- scores: S = Q K^T * scale, kt-PAIRS (128x256 per block) ----
// grid 576: b = bid%8 (-> XCD b); t = 71 - bid/8 decoded to (qt, kt2), kt0=2*kt2.
// Sub-tile kt = kt0 + wn (wave-n IS the sub-tile). Store only kt<=qt; diagonal
// sub-tile masked with -30000 (softmax exp -> 0).
__global__ __launch_bounds__(256, 2) void k_scores(const _Float16* __restrict__ Qb,
                                                   const _Float16* __restrict__ Kb,
                                                   _Float16* __restrict__ P)
{
  __shared__ __align__(16) _Float16 Bs0[256*64], Bs1[256*64];   // 64 KB
  const int bid = blockIdx.x;
  const int b = bid & 7;
  const int t = 71 - (bid >> 3);        // heavy (large qt) blocks first
  int qt = 0, accum = 0;
  while (accum + (qt/2 + 1) <= t) { accum += qt/2 + 1; ++qt; }
  const int kt2 = t - accum;
  const int kt0 = kt2 * 2;

  f32x4 acc[4][8] = {};
  run_kloop_dA(Qb + ((size_t)b*2048 + qt*128)*512,
               Kb + ((size_t)b*2048 + kt0*128)*512,
               512, 512, 8, Bs0, Bs1, acc);

  const int tid = threadIdx.x;
  const int lane = tid & 63, w = tid >> 6;
  const int wm = w >> 1, wn = w & 1;
  const int fr = lane & 15, fq = lane >> 4;

  const int kt = kt0 + wn;
  if (kt <= qt) {
    const bool diag = (kt == qt);
    #pragma unroll
    for (int i = 0; i < 4; ++i) {
      const int rl = wm*64 + i*16 + fq*4;
      #pragma unroll
      for (int j = 0; j < 8; ++j) {
        const int cl = j*16 + fr;           // col within sub-tile
        #pragma unroll
        for (int r = 0; r < 4; ++r) {
          const float sc = acc[i][j][r] * SCALE_QK;
          const bool msk = diag && (cl > rl + r);
          P[((size_t)b*2048 + qt*128 + rl + r) * 2048 + kt*128 + cl] =
              msk ? (_Float16)(-30000.0f) : (_Float16)sc;
        }
      }
    }
  }
}

// ---- in-place causal row softmax; one wave per row; row cached in regs ----
__global__ __launch_bounds__(256) void k_softmax(_Float16* __restrict__ P)
{
  const int lane = threadIdx.x & 63;
  const int row  = blockIdx.x * 4 + (threadIdx.x >> 6);  // 0..16383 (= b*2048+q)
  const int qIdx = row & 2047;
  _Float16* p = P + (size_t)row * 2048;
  const int L    = qIdx + 1;
  const int Lpad = ((qIdx >> 7) + 1) * 128;

  half8 xb[4];
  float m = -1e30f, s = 0.f;
  #pragma unroll
  for (int c = 0; c < 4; ++c) {
    const int i0 = lane * 8 + c * 512;
    if (i0 < Lpad) {
      half8 x = *(const half8*)(p + i0);
      xb[c] = x;
      float xv[8];
      #pragma unroll
      for (int j = 0; j < 8; ++j) xv[j] = (i0 + j < L) ? (float)x[j] : -1e30f;
      float cm = xv[0];
      #pragma unroll
      for (int j = 1; j < 8; ++j) cm = fmaxf(cm, xv[j]);
      const float mn = fmaxf(m, cm);
      float cs = 0.f;
      #pragma unroll
      for (int j = 0; j < 8; ++j) cs += __expf(xv[j] - mn);
      s = s * __expf(m - mn) + cs;
      m = mn;
    }
  }
  #pragma unroll
  for (int d = 1; d < 64; d <<= 1) {
    const float mo = __shfl_xor(m, d, 64);
    const float so = __shfl_xor(s, d, 64);
    const float mn = fmaxf(m, mo);
    s = s * __expf(m - mn) + so * __expf(mo - mn);
    m = mn;
  }
  const float inv = 1.0f / s;

  #pragma unroll
  for (int c = 0; c < 4; ++c) {
    const int i0 = lane * 8 + c * 512;
    if (i0 < Lpad) {
      half8 x = xb[c];
      half8 o;
      #pragma unroll
      for (int j = 0; j < 8; ++j)
        o[j] = (i0 + j < L) ? (_Float16)(__expf((float)x[j] - m) * inv) : (_Float16)0.f;
      *(half8*)(p + i0) = o;
    }
  }
}

// ---- out = P @ V, dt-pairs (128x256 of Out per block), causal K-extent ----
// grid 256: b = bid%8 (-> XCD b); r = bid/8 in [0,32): qi=r/2 interleaved
// long/short, dt2=r%2. B-operand = Vt[d][s] rows dt2*256..+256.
__global__ __launch_bounds__(256, 2) void k_pv(const _Float16* __restrict__ P,
                                               const _Float16* __restrict__ Vt,
                                               float* __restrict__ Out)
{
  __shared__ __align__(16) _Float16 Bs0[256*64], Bs1[256*64];   // 64 KB
  const int bid = blockIdx.x;
  const int b = bid & 7;
  const int r0 = bid >> 3;
  const int qi = r0 >> 1, dt2 = r0 & 1;
  const int qt = (qi & 1) ? (15 - (qi >> 1)) : (qi >> 1);

  f32x4 acc[4][8] = {};
  run_kloop_dA(P  + ((size_t)b*2048 + qt*128)*2048,
               Vt + ((size_t)b*512  + dt2*256)*2048,
               2048, 2048, (qt + 1) * 2, Bs0, Bs1, acc);

  const int tid = threadIdx.x;
  const int lane = tid & 63, w = tid >> 6;
  const int wm = w >> 1, wn = w & 1;
  const int fr = lane & 15, fq = lane >> 4;
  #pragma unroll
  for (int i = 0; i < 4; ++i) {
    const int row = qt*128 + wm*64 + i*16 + fq*4;
    #pragma unroll
    for (int j = 0; j < 8; ++j) {
      const int col = dt2*256 + wn*128 + j*16 + fr;
      #pragma unroll
      for (int r = 0; r < 4; ++r)
        Out[((size_t)b*2048 + row + r) * 512 + col] = acc[i][j][r];
    }
  }
}

extern "C" void kernel_launch(void* const* d_in, const int* in_sizes, int n_in,
                              void* d_out, int out_size, void* d_ws, size_t ws_size,
                              hipStream_t stream) {
  (void)in_sizes; (void)n_in; (void)out_size;
  const float* q  = (const float*)d_in[0];
  const float* k  = (const float*)d_in[1];
  const float* v  = (const float*)d_in[2];
  // d_in[3] = causal mask: always tril per setup; implemented structurally.
  const float* Wq = (const float*)d_in[4];
  const float* bq = (const float*)d_in[5];
  const float* Wk = (const float*)d_in[6];
  const float* bk = (const float*)d_in[7];
  const float* Wv = (const float*)d_in[8];
  const float* bv = (const float*)d_in[9];

  const size_t OFF_P  = 0;
  const size_t OFF_Q  = (size_t)64 << 20;
  const size_t OFF_K  = (size_t)80 << 20;
  const size_t OFF_VT = (size_t)112 << 20;
  const size_t OFF_W  = (size_t)128 << 20;
  const size_t NEEDED = OFF_W + (size_t)3 * 512 * 512 * sizeof(_Float16);
  if (ws_size < NEEDED) return;  // diagnostic: poison-level absmax => ws too small

  char* ws = (char*)d_ws;
  _Float16* P  = (_Float16*)(ws + OFF_P);
  _Float16* Qb = (_Float16*)(ws + OFF_Q);
  _Float16* Kb = (_Float16*)(ws + OFF_K);
  _Float16* Vt = (_Float16*)(ws + OFF_VT);
  _Float16* Wb = (_Float16*)(ws + OFF_W);
  float* Out = (float*)d_out;

  k_cvtw   <<<dim3(384),  dim3(256), 0, stream>>>(Wq, Wk, Wv, Wb);
  k_proj   <<<dim3(1536), dim3(256), 0, stream>>>(q, k, v, Wb, bq, bk, bv, Qb, Kb, Vt);
  k_scores <<<dim3(576),  dim3(256), 0, stream>>>(Qb, Kb, P);
  k_softmax<<<dim3(4096), dim3(256), 0, stream>>>(P);
  k_pv     <<<dim3(256),  dim3(256), 0, stream>>>(P, Vt, Out);
}

// Round 6
// 262.717 us; speedup vs baseline: 1.3702x; 1.3702x over previous
//
// AttentionModel: fused QKV projection + causal softmax attention, MI355X/gfx950.
// Round 9: m97 replication. R8's 1-block/CU k_pv calibrated the constant:
// ~7000 cy/phase regardless of MFMA count => pure exposed stage latency; the
// only proven hiding mechanism is other blocks on the CU (m97: single-buffer,
// 2 barriers/K-step, 32KB LDS, 3 blocks/CU -> 874 TF; m114 overlap).
//  - run_kloop_sb: SINGLE As+Bs (32 KB), per K-step stage->sync->compute->sync.
//    No dbuf state (R4/R6/R7 proved dbuf+counted-vmcnt buy nothing at 2/CU).
//    Proven BK=64 zero-conflict swizzle + fragment math unchanged.
//  - launch_bounds: proj (256,3) ~170 VGPR cap; scores/pv (256,4) 128 cap ->
//    3-4 blocks/CU (12-16 waves) vs previous 2.
//  - k_pv back to 512 blocks (dt=4, qt long/short interleave: phase-balanced
//    pairs per CU). k_scores back to 1088 triangular 128^2.
//  - keep: proj with fused V-transpose (k_trans deleted), R4 softmax.
// ws layout (bytes): P 0..64M | Qb 64M | Kb 80M | Vt 112M | Wf16 128M

#include <hip/hip_runtime.h>
#include <stdint.h>
#include <stddef.h>
#include <math.h>

typedef _Float16 half8 __attribute__((ext_vector_type(8)));
typedef float f32x4 __attribute__((ext_vector_type(4)));

#define SCALE_QK 0.04419417382415922f  // 1/sqrt(512)

__device__ __forceinline__ void gload16(const void* g, void* lds) {
  __builtin_amdgcn_global_load_lds(
      (const __attribute__((address_space(1))) void*)g,
      (__attribute__((address_space(3))) void*)lds,
      16, 0, 0);
}

// K-loop: C[128x128] = A[128xK] * B^T (B stored [N][K]), f16 MFMA, BK=64.
// SINGLE-buffered (m97 structure): stage -> sync -> compute -> sync.
// LDS contract: element (row r, 8-group g) at halfword r*64 + (g^(r&7))*8.
template<bool A_F32>
__device__ __forceinline__ void run_kloop_sb(const void* Arow0, const _Float16* Brow0,
                                             int lda, int ldb, int kIters,
                                             _Float16* As, _Float16* Bs,
                                             f32x4 (&acc)[4][4])
{
  const int tid  = threadIdx.x;
  const int lane = tid & 63;
  const int w    = tid >> 6;
  const int wm   = w >> 1, wn = w & 1;
  const int srow = tid >> 3;          // staging row within 32-row chunk
  const int sg   = tid & 7;           // staging 8-elem group slot
  const int swz  = sg ^ (srow & 7);   // swizzled group (source side)
  const int fr   = lane & 15;         // fragment m/n within 16
  const int fq   = lane >> 4;         // k-quad
  const int fx   = lane & 7;          // read-side swizzle

  for (int it = 0; it < kIters; ++it) {
    const int k0 = it * 64;
    if constexpr (A_F32) {
      const float* A = (const float*)Arow0;
      f32x4 preF[8];
      #pragma unroll
      for (int i = 0; i < 4; ++i) {
        const float* src = A + (size_t)(i*32 + srow) * lda + (k0 + sg*8);
        preF[2*i]   = *(const f32x4*)src;
        preF[2*i+1] = *(const f32x4*)(src + 4);
      }
      #pragma unroll
      for (int i = 0; i < 4; ++i)
        gload16(Brow0 + (size_t)(i*32 + srow) * ldb + (k0 + swz*8), Bs + i*2048 + w*512);
      #pragma unroll
      for (int i = 0; i < 4; ++i) {     // cvt + LDS write (compiler waits preF)
        f32x4 x = preF[2*i], y = preF[2*i+1];
        half8 h;
        h[0]=(_Float16)x[0]; h[1]=(_Float16)x[1]; h[2]=(_Float16)x[2]; h[3]=(_Float16)x[3];
        h[4]=(_Float16)y[0]; h[5]=(_Float16)y[1]; h[6]=(_Float16)y[2]; h[7]=(_Float16)y[3];
        *(half8*)(As + (i*32 + srow)*64 + swz*8) = h;
      }
    } else {
      const _Float16* A = (const _Float16*)Arow0;
      #pragma unroll
      for (int i = 0; i < 4; ++i)
        gload16(A + (size_t)(i*32 + srow) * lda + (k0 + swz*8), As + i*2048 + w*512);
      #pragma unroll
      for (int i = 0; i < 4; ++i)
        gload16(Brow0 + (size_t)(i*32 + srow) * ldb + (k0 + swz*8), Bs + i*2048 + w*512);
    }
    __syncthreads();   // drains vmcnt (gload_lds) + lgkm (A writes): tile ready

    #pragma unroll
    for (int ks = 0; ks < 2; ++ks) {
      half8 av[4], bv[4];
      const int slot = (ks*4 + fq) ^ fx;
      #pragma unroll
      for (int i = 0; i < 4; ++i) {
        av[i] = *(const half8*)(As + (wm*64 + i*16 + fr)*64 + slot*8);
        bv[i] = *(const half8*)(Bs + (wn*64 + i*16 + fr)*64 + slot*8);
      }
      #pragma unroll
      for (int i = 0; i < 4; ++i) {
        #pragma unroll
        for (int j = 0; j < 4; ++j)
          acc[i][j] = __builtin_amdgcn_mfma_f32_16x16x32_f16(av[i], bv[j], acc[i][j], 0, 0, 0);
      }
    }
    __syncthreads();   // all reads done before next iteration's overwrite
  }
}

// ---- weights fp32 -> f16 (3 x 512x512 concatenated) ----
__global__ __launch_bounds__(256) void k_cvtw(const float* __restrict__ Wq,
                                              const float* __restrict__ Wk,
                                              const float* __restrict__ Wv,
                                              _Float16* __restrict__ Wb)
{
  const int t = blockIdx.x * 256 + threadIdx.x;
  const int base = t * 8;
  const int z = base >> 18;
  const int off = base & 262143;
  const float* src = (z == 0) ? Wq : ((z == 1) ? Wk : Wv);
  f32x4 a = *(const f32x4*)(src + off);
  f32x4 b = *(const f32x4*)(src + off + 4);
  half8 h;
  h[0]=(_Float16)a[0]; h[1]=(_Float16)a[1]; h[2]=(_Float16)a[2]; h[3]=(_Float16)a[3];
  h[4]=(_Float16)b[0]; h[5]=(_Float16)b[1]; h[6]=(_Float16)b[2]; h[7]=(_Float16)b[3];
  *(half8*)(Wb + base) = h;
}

// ---- projections: X[16384x512](fp32) @ W^T + bias -> f16; V direct-transposed ----
// 1D grid 1536: xcd = bid%8; panel p = xcd*48 + i/4; nt = i%4; z = p/128, mt = p%128.
// LDS: union of {As 16KB + Bs 16KB} and the V-transpose tile [128][132] (33.8KB).
__global__ __launch_bounds__(256, 3) void k_proj(const float* __restrict__ q,
                                                 const float* __restrict__ k,
                                                 const float* __restrict__ v,
                                                 const _Float16* __restrict__ Wb,
                                                 const float* __restrict__ bq,
                                                 const float* __restrict__ bk,
                                                 const float* __restrict__ bv,
                                                 _Float16* __restrict__ Qb,
                                                 _Float16* __restrict__ Kb,
                                                 _Float16* __restrict__ Vt)
{
  __shared__ __align__(16) _Float16 LDSbuf[128*132];   // 33.8 KB union
  _Float16* As = LDSbuf;
  _Float16* Bs = LDSbuf + 8192;

  const int bid = blockIdx.x;
  const int xcd = bid & 7, i = bid >> 3;
  const int p = xcd * 48 + (i >> 2);
  const int nt = i & 3;
  const int z = p >> 7, mt = p & 127;

  const float* A     = (z == 0) ? q  : (z == 1) ? k  : v;
  const float* bia   = (z == 0) ? bq : (z == 1) ? bk : bv;
  const _Float16* B  = Wb + (size_t)z * 512 * 512;

  f32x4 acc[4][4] = {};
  run_kloop_sb<true>(A + (size_t)mt*128*512, B + (size_t)nt*128*512, 512, 512, 8,
                     As, Bs, acc);

  const int tid = threadIdx.x;
  const int lane = tid & 63, w = tid >> 6;
  const int wm = w >> 1, wn = w & 1;
  const int fr = lane & 15, fq = lane >> 4;   // C/D: col=lane&15, row=(lane>>4)*4+reg

  if (z < 2) {
    _Float16* C = (z == 0) ? Qb : Kb;
    #pragma unroll
    for (int j = 0; j < 4; ++j) {
      const int col = nt*128 + wn*64 + j*16 + fr;
      const float bval = bia[col];
      #pragma unroll
      for (int i2 = 0; i2 < 4; ++i2) {
        const int row = mt*128 + wm*64 + i2*16 + fq*4;
        #pragma unroll
        for (int r = 0; r < 4; ++r)
          C[(size_t)(row + r) * 512 + col] = (_Float16)(acc[i2][j][r] + bval);
      }
    }
  } else {
    // V: stage transposed tile in LDS [col 128][row 128 + pad 4], write Vt coalesced.
    // store: 16 fr-lanes at stride 264B -> banks {0,2,..,30} distinct; read: b128
    // contiguous 16 lanes -> 2-way (free). (kloop ended with syncthreads: LDS free)
    _Float16* sm = LDSbuf;
    #pragma unroll
    for (int j = 0; j < 4; ++j) {
      const int colloc = wn*64 + j*16 + fr;
      const float bval = bia[nt*128 + colloc];
      #pragma unroll
      for (int i2 = 0; i2 < 4; ++i2) {
        const int rowloc = wm*64 + i2*16 + fq*4;
        #pragma unroll
        for (int r = 0; r < 4; ++r)
          sm[colloc*132 + rowloc + r] = (_Float16)(acc[i2][j][r] + bval);
      }
    }
    __syncthreads();
    const int bb = mt >> 4, s0 = (mt & 15) * 128;
    #pragma unroll
    for (int q8 = 0; q8 < 8; ++q8) {
      const int dloc = q8*16 + (tid >> 4);
      const int ch   = tid & 15;
      half8 o = *(const half8*)&sm[dloc*132 + ch*8];
      *(half8*)(Vt + ((size_t)bb*512 + nt*128 + dloc)*2048 + s0 + ch*8) = o;
    }
  }
}

// ---- scores: S = Q K^T * scale ----
// 1D grid 1088: b = bid%8 (-> XCD b); t = bid/8 triangular-decoded to (qt,kt),
// kt<=qt. Per-batch Q+K (4MB) is L2-resident on its XCD.
__global__ __launch_bounds__(256, 4) void k_scores(const _Float16* __restrict__ Qb,
                                                   const _Float16* __restrict__ Kb,
                                                   _Float16* __restrict__ P)
{
  __shared__ __align__(16) _Float16 As[128*64], Bs[128*64];   // 32 KB
  const int bid = blockIdx.x;
  const int b = bid & 7;
  const int t = bid >> 3;
  int qt = (int)((sqrtf(8.0f * (float)t + 1.0f) - 1.0f) * 0.5f);
  int base = (qt * (qt + 1)) >> 1;
  if (t < base)                { --qt; base = (qt * (qt + 1)) >> 1; }
  else if (t >= base + qt + 1) { ++qt; base = (qt * (qt + 1)) >> 1; }
  const int kt = t - base;

  f32x4 acc[4][4] = {};
  run_kloop_sb<false>(Qb + ((size_t)b*2048 + qt*128)*512,
                      Kb + ((size_t)b*2048 + kt*128)*512,
                      512, 512, 8, As, Bs, acc);
  const int lane = threadIdx.x & 63, w = threadIdx.x >> 6;
  const int wm = w >> 1, wn = w & 1;
  const int fr = lane & 15, fq = lane >> 4;
  #pragma unroll
  for (int i = 0; i < 4; ++i) {
    const int row = qt*128 + wm*64 + i*16 + fq*4;
    #pragma unroll
    for (int j = 0; j < 4; ++j) {
      const int col = kt*128 + wn*64 + j*16 + fr;
      #pragma unroll
      for (int r = 0; r < 4; ++r)
        P[((size_t)b*2048 + row + r) * 2048 + col] = (_Float16)(acc[i][j][r] * SCALE_QK);
    }
  }
}

// ---- in-place causal row softmax; one wave per row; row cached in regs ----
__global__ __launch_bounds__(256) void k_softmax(_Float16* __restrict__ P)
{
  const int lane = threadIdx.x & 63;
  const int row  = blockIdx.x * 4 + (threadIdx.x >> 6);  // 0..16383 (= b*2048+q)
  const int qIdx = row & 2047;
  _Float16* p = P + (size_t)row * 2048;
  const int L    = qIdx + 1;
  const int Lpad = ((qIdx >> 7) + 1) * 128;     // PV kernel reads up to here

  half8 xb[4];
  float m = -1e30f, s = 0.f;
  #pragma unroll
  for (int c = 0; c < 4; ++c) {
    const int i0 = lane * 8 + c * 512;
    if (i0 < Lpad) {
      half8 x = *(const half8*)(p + i0);
      xb[c] = x;
      float xv[8];
      #pragma unroll
      for (int j = 0; j < 8; ++j) xv[j] = (i0 + j < L) ? (float)x[j] : -1e30f;
      float cm = xv[0];
      #pragma unroll
      for (int j = 1; j < 8; ++j) cm = fmaxf(cm, xv[j]);
      const float mn = fmaxf(m, cm);
      float cs = 0.f;
      #pragma unroll
      for (int j = 0; j < 8; ++j) cs += __expf(xv[j] - mn);
      s = s * __expf(m - mn) + cs;
      m = mn;
    }
  }
  #pragma unroll
  for (int d = 1; d < 64; d <<= 1) {
    const float mo = __shfl_xor(m, d, 64);
    const float so = __shfl_xor(s, d, 64);
    const float mn = fmaxf(m, mo);
    s = s * __expf(m - mn) + so * __expf(mo - mn);
    m = mn;
  }
  const float inv = 1.0f / s;

  #pragma unroll
  for (int c = 0; c < 4; ++c) {
    const int i0 = lane * 8 + c * 512;
    if (i0 < Lpad) {
      half8 x = xb[c];
      half8 o;
      #pragma unroll
      for (int j = 0; j < 8; ++j)
        o[j] = (i0 + j < L) ? (_Float16)(__expf((float)x[j] - m) * inv) : (_Float16)0.f;
      *(half8*)(p + i0) = o;
    }
  }
}

// ---- out = P @ V  (B-operand = Vt[d][s]), causal K-extent ----
// 1D grid 512: b = bid%8 (-> XCD b); r = bid/8 in [0,64): qi=r/4 interleaved
// long/short (phase-balanced block pairs per CU), dt=r%4 (P rows L2-hot).
__global__ __launch_bounds__(256, 4) void k_pv(const _Float16* __restrict__ P,
                                               const _Float16* __restrict__ Vt,
                                               float* __restrict__ Out)
{
  __shared__ __align__(16) _Float16 As[128*64], Bs[128*64];   // 32 KB
  const int bid = blockIdx.x;
  const int b = bid & 7;
  const int r0 = bid >> 3;
  const int qi = r0 >> 2, dt = r0 & 3;
  const int qt = (qi & 1) ? (15 - (qi >> 1)) : (qi >> 1);

  f32x4 acc[4][4] = {};
  run_kloop_sb<false>(P  + ((size_t)b*2048 + qt*128)*2048,
                      Vt + ((size_t)b*512  + dt*128)*2048,
                      2048, 2048, (qt + 1) * 2, As, Bs, acc);
  const int lane = threadIdx.x & 63, w = threadIdx.x >> 6;
  const int wm = w >> 1, wn = w & 1;
  const int fr = lane & 15, fq = lane >> 4;
  #pragma unroll
  for (int i = 0; i < 4; ++i) {
    const int row = qt*128 + wm*64 + i*16 + fq*4;
    #pragma unroll
    for (int j = 0; j < 4; ++j) {
      const int col = dt*128 + wn*64 + j*16 + fr;
      #pragma unroll
      for (int r = 0; r < 4; ++r)
        Out[((size_t)b*2048 + row + r) * 512 + col] = acc[i][j][r];
    }
  }
}

extern "C" void kernel_launch(void* const* d_in, const int* in_sizes, int n_in,
                              void* d_out, int out_size, void* d_ws, size_t ws_size,
                              hipStream_t stream) {
  (void)in_sizes; (void)n_in; (void)out_size;
  const float* q  = (const float*)d_in[0];
  const float* k  = (const float*)d_in[1];
  const float* v  = (const float*)d_in[2];
  // d_in[3] = causal mask: always tril per setup; implemented structurally.
  const float* Wq = (const float*)d_in[4];
  const float* bq = (const float*)d_in[5];
  const float* Wk = (const float*)d_in[6];
  const float* bk = (const float*)d_in[7];
  const float* Wv = (const float*)d_in[8];
  const float* bv = (const float*)d_in[9];

  const size_t OFF_P  = 0;
  const size_t OFF_Q  = (size_t)64 << 20;
  const size_t OFF_K  = (size_t)80 << 20;
  const size_t OFF_VT = (size_t)112 << 20;
  const size_t OFF_W  = (size_t)128 << 20;
  const size_t NEEDED = OFF_W + (size_t)3 * 512 * 512 * sizeof(_Float16);
  if (ws_size < NEEDED) return;  // diagnostic: poison-level absmax => ws too small

  char* ws = (char*)d_ws;
  _Float16* P  = (_Float16*)(ws + OFF_P);
  _Float16* Qb = (_Float16*)(ws + OFF_Q);
  _Float16* Kb = (_Float16*)(ws + OFF_K);
  _Float16* Vt = (_Float16*)(ws + OFF_VT);
  _Float16* Wb = (_Float16*)(ws + OFF_W);
  float* Out = (float*)d_out;

  k_cvtw   <<<dim3(384),  dim3(256), 0, stream>>>(Wq, Wk, Wv, Wb);
  k_proj   <<<dim3(1536), dim3(256), 0, stream>>>(q, k, v, Wb, bq, bk, bv, Qb, Kb, Vt);
  k_scores <<<dim3(1088), dim3(256), 0, stream>>>(Qb, Kb, P);
  k_softmax<<<dim3(4096), dim3(256), 0, stream>>>(P);
  k_pv     <<<dim3(512),  dim3(256), 0, stream>>>(P, Vt, Out);
}